// Round 10
// baseline (370.617 us; speedup 1.0000x reference)
//
#include <hip/hip_runtime.h>
#include <math.h>

typedef unsigned int u32;

#define N_TOTAL 500000
#define P_NODES 21
#define KNEG    5
#define DDIM    128
#define BATCH   1024
#define N_PAIRS 185
#define N_NEG   (N_PAIRS * KNEG)            // 925
#define NNEG_TOT (N_PAIRS * BATCH * KNEG)   // 947200
#define C_ROWS  (BATCH * P_NODES)           // 21504

#define SPAN    128                          // table rows per bucket (64 KB)
#define NBUCKET ((N_TOTAL + SPAN - 1) / SPAN) // 3907
#define CAP     384                          // mean 242, sigma 15.6 -> 9 sigma margin
#define C8_BYTES ((size_t)C_ROWS * DDIM)     // 2,752,512 (fp8)
#define CNT_OFF  C8_BYTES
#define REC_OFF  (CNT_OFF + 16384)
#define WS_NEEDED (REC_OFF + (size_t)NBUCKET * CAP * 4)   // ~8.8 MB

struct Pairs { unsigned char pi[N_PAIRS]; unsigned char pj[N_PAIRS]; };

constexpr Pairs make_pairs() {
    Pairs p{};
    int n = 0;
    for (int i = 0; i < P_NODES; ++i) {
        int jlo = (i - KNEG > 0) ? i - KNEG : 0;
        int jhi = (i + KNEG < P_NODES) ? i + KNEG : P_NODES;
        for (int j = jlo; j < jhi; ++j) { p.pi[n] = (unsigned char)i; p.pj[n] = (unsigned char)j; ++n; }
    }
    return p;
}

__constant__ Pairs PAIRS = make_pairs();

__device__ __forceinline__ float lsig(float x) {
    return -__logf(1.f + __expf(-x));   // dots are tiny; no overflow risk
}

__device__ __forceinline__ float dot4(float4 a, float4 b) {
    return fmaf(a.x, b.x, fmaf(a.y, b.y, fmaf(a.z, b.z, a.w * b.w)));
}

__device__ __forceinline__ int divk(int q) {        // q/5 exact for q < 2^18
    return (int)(((u32)q * 52429u) >> 18);
}

// ---- custom e4m3 (bias 7) codec, pure bit ops (same as R8 which passed absmax 0.0) ----
__device__ __forceinline__ u32 enc1(float x) {
    u32 u = __float_as_uint(x * 0x1p-120f);          // target bits at [26:20]
    u32 s = (u >> 24) & 0x80u;
    u &= 0x7fffffffu;
    u += 0x7FFFFu + ((u >> 20) & 1u);                // RNE at bit 20
    return s | ((u >> 20) & 0x7fu);
}
__device__ __forceinline__ float dec1(u32 b) {
    u32 bits = ((b << 20) & 0x07f00000u) | ((b << 24) & 0x80000000u);
    return __uint_as_float(bits) * 0x1p+120f;
}
__device__ __forceinline__ float dot_pk(u32 d, float4 c) {
    float r;
    r  = dec1( d         & 0xffu) * c.x;
    r += dec1((d >>  8u) & 0xffu) * c.y;
    r += dec1((d >> 16u) & 0xffu) * c.z;
    r += dec1( d >> 24u         ) * c.w;
    return r;
}

__global__ void kzero(float* __restrict__ out) {
    if (threadIdx.x == 0) out[0] = 0.f;
}

// ---- k_c8: fp8-encode the 21504 context rows (2.75 MB -> L2-resident) ----
// Dword layout PERMUTED so k_serve's lane m (owning float4-slots m,m+8,m+16,m+24)
// reads them as one contiguous uint4: slot s stored at dword pos 4*(s&7)+(s>>3).
__global__ __launch_bounds__(256) void k_c8(
    const float* __restrict__ emb, const int* __restrict__ path, u32* __restrict__ C8)
{
    int t   = blockIdx.x * 256 + threadIdx.x;        // 688128 = 21504 rows * 32 slots
    int cid = t >> 5, c = t & 31;
    int b   = cid / P_NODES;
    int i   = cid - b * P_NODES;
    int row = path[b * P_NODES + i];
    float4 v = ((const float4*)(emb + (size_t)row * DDIM))[c];
    u32 w = enc1(v.x) | (enc1(v.y) << 8) | (enc1(v.z) << 16) | (enc1(v.w) << 24);
    C8[(size_t)cid * 32 + 4 * (c & 7) + (c >> 3)] = w;   // permuted within the 128B row
}

// ---- k_bin: bin the 947200 neg tasks by 128-row table span ----
__global__ __launch_bounds__(256) void k_bin(
    const int* __restrict__ neg, int* __restrict__ cnt, u32* __restrict__ rec)
{
    int n   = blockIdx.x * 256 + threadIdx.x;        // 947200 exactly
    int p   = divk(n >> 10);                         // n / 5120
    int rem = n - p * 5120;
    int b   = divk(rem);                             // rem / 5
    int idx = neg[n];
    int bucket = idx >> 7;
    int lr     = idx & (SPAN - 1);
    int cid    = b * P_NODES + PAIRS.pi[p];
    int slot = atomicAdd(&cnt[bucket], 1);
    if (slot < CAP)
        rec[(size_t)bucket * CAP + slot] = ((u32)cid << 7) | (u32)lr;
}

// ---- k_pos: exact-f32 positive dots, one block per b ----
__global__ __launch_bounds__(256) void k_pos(
    const float* __restrict__ emb, const int* __restrict__ path, float* __restrict__ out)
{
    __shared__ float4 crow[P_NODES * 32];
    __shared__ int pidx[P_NODES];
    __shared__ unsigned char spi[N_PAIRS], spj[N_PAIRS];
    const int b = blockIdx.x, t = threadIdx.x;
    if (t < P_NODES) pidx[t] = path[b * P_NODES + t];
    if (t < N_PAIRS) { spi[t] = PAIRS.pi[t]; spj[t] = PAIRS.pj[t]; }
    __syncthreads();
    for (int e = t; e < P_NODES * 32; e += 256) {
        int r = e >> 5, c = e & 31;
        crow[r * 32 + ((c + r) & 31)] = ((const float4*)(emb + (size_t)pidx[r] * DDIM))[c];
    }
    __syncthreads();
    const int g = t >> 3, m = t & 7;
    float acc = 0.f;
    for (int s = g; s < N_PAIRS; s += 32) {
        int ci = spi[s], cj = spj[s];
        float part = 0.f;
        #pragma unroll
        for (int i = 0; i < 4; ++i) {
            int c = m + 8 * i;
            part += dot4(crow[cj * 32 + ((c + cj) & 31)], crow[ci * 32 + ((c + ci) & 31)]);
        }
        part += __shfl_xor(part, 1);
        part += __shfl_xor(part, 2);
        part += __shfl_xor(part, 4);
        acc += lsig(part);                    // counted 8x (m duplicates)
    }
    acc += __shfl_xor(acc, 32);
    acc += __shfl_xor(acc, 16);
    acc += __shfl_xor(acc, 8);
    acc += __shfl_xor(acc, 4);
    acc += __shfl_xor(acc, 2);
    acc += __shfl_xor(acc, 1);
    if ((t & 63) == 0)
        atomicAdd(out, acc * (-1.f / (8.f * (float)BATCH)));
}

// ---- k_serve: one block per span; stream 64KB of emb -> LDS (sequential!),
// serve ~242 tasks: neg row exact-f32 from LDS, c-row = 1 fp8 line from L2-hot C8 ----
__global__ __launch_bounds__(256) void k_serve(
    const float* __restrict__ emb, const u32* __restrict__ C8,
    const int* __restrict__ cnt, const u32* __restrict__ rec,
    float* __restrict__ out)
{
    __shared__ float4 span[SPAN * 32];        // 64 KB, slot rotated by row
    const int bucket = blockIdx.x;
    const int t      = threadIdx.x;
    const size_t base = (size_t)bucket * SPAN;

    const float4* emb4 = (const float4*)emb;
    #pragma unroll
    for (int j = 0; j < 16; ++j) {            // 4096 float4s, fully coalesced
        int e = j * 256 + t;
        int r = e >> 5, c = e & 31;
        size_t gr = base + r;
        float4 v = (gr < (size_t)N_TOTAL) ? emb4[gr * 32 + c]
                                          : make_float4(0.f, 0.f, 0.f, 0.f);
        span[r * 32 + ((c + r) & 31)] = v;
    }
    __syncthreads();

    const int count = min(cnt[bucket], CAP);
    const int g = t >> 3, m = t & 7;
    const uint4* C8u = (const uint4*)C8;
    float acc = 0.f;

    for (int s0 = 0; s0 < count; s0 += 128) {
        uint4 rv[4];
        int   lrv[4];
        bool  vv[4];
        #pragma unroll
        for (int k = 0; k < 4; ++k) {
            int s = s0 + g * 4 + k;
            bool v = s < count;
            vv[k] = v;
            u32 rc = rec[(size_t)bucket * CAP + (v ? s : 0)];
            lrv[k] = (int)(rc & (SPAN - 1));
            int cid = (int)(rc >> 7);
            rv[k] = C8u[(size_t)cid * 8 + m];           // 8 lanes = one 128B line
        }
        #pragma unroll
        for (int k = 0; k < 4; ++k) {
            int lr = lrv[k];
            // rv dword i holds float4-slot m+8i (permuted at build) -> conflict-free LDS
            float part;
            part  = dot_pk(rv[k].x, span[lr * 32 + ((m      + lr) & 31)]);
            part += dot_pk(rv[k].y, span[lr * 32 + ((m + 8  + lr) & 31)]);
            part += dot_pk(rv[k].z, span[lr * 32 + ((m + 16 + lr) & 31)]);
            part += dot_pk(rv[k].w, span[lr * 32 + ((m + 24 + lr) & 31)]);
            part += __shfl_xor(part, 1);
            part += __shfl_xor(part, 2);
            part += __shfl_xor(part, 4);
            if (vv[k]) acc += lsig(-part);    // counted 8x
        }
    }

    acc += __shfl_xor(acc, 32);
    acc += __shfl_xor(acc, 16);
    acc += __shfl_xor(acc, 8);
    acc += __shfl_xor(acc, 4);
    acc += __shfl_xor(acc, 2);
    acc += __shfl_xor(acc, 1);
    if ((t & 63) == 0)
        atomicAdd(out, acc * (-1.f / (8.f * (float)BATCH)));
}

// ================= fallback (R6 kernel, verbatim) if ws is too small =================
#define NTASK_F (N_PAIRS + N_NEG)
#define HALF_T  (NTASK_F / 2)

__global__ __launch_bounds__(256) void mp2v_fallback(
    const float* __restrict__ emb, const int* __restrict__ path,
    const int* __restrict__ neg, float* __restrict__ out)
{
    __shared__ float4 crow[P_NODES * 32];
    __shared__ int    nidxf[N_NEG];
    __shared__ int    pidx[P_NODES];
    __shared__ unsigned char spi[N_PAIRS];
    __shared__ unsigned char spj[N_PAIRS];

    const int blk = blockIdx.x;
    const int b   = blk >> 1;
    const int q0  = (blk & 1) * HALF_T;
    const int q1  = q0 + HALF_T;
    const int t   = threadIdx.x;

    if (t < P_NODES) pidx[t] = path[b * P_NODES + t];
    if (t < N_PAIRS) { spi[t] = PAIRS.pi[t]; spj[t] = PAIRS.pj[t]; }
    for (int q = t; q < N_NEG; q += 256) {
        int p = divk(q);
        int k = q - p * KNEG;
        nidxf[q] = neg[(size_t)p * (BATCH * KNEG) + b * KNEG + k];
    }
    __syncthreads();
    for (int e = t; e < P_NODES * 32; e += 256) {
        int r = e >> 5, c = e & 31;
        float4 val = ((const float4*)(emb + (size_t)pidx[r] * DDIM))[c];
        crow[r * 32 + ((c + r) & 31)] = val;
    }
    __syncthreads();

    const int g = t >> 3, m = t & 7;
    const float4* emb4 = (const float4*)emb;
    float acc = 0.f;

    for (int base = q0; base < q1; base += 128) {
        float4 rv[4][4];
        int civ[4]; float sg[4]; bool vv[4];
        #pragma unroll
        for (int k = 0; k < 4; ++k) {
            int qq = base + g * 4 + k;
            bool v = qq < q1; vv[k] = v;
            int qc = v ? qq : q0;
            if (qc < N_NEG) {
                int p = divk(qc);
                civ[k] = spi[p]; sg[k] = -1.f;
                const float4* R = emb4 + (size_t)nidxf[qc] * 32;
                #pragma unroll
                for (int i = 0; i < 4; ++i) rv[k][i] = R[m + 8 * i];
            } else {
                int pp = qc - N_NEG;
                int cj = spj[pp];
                civ[k] = spi[pp]; sg[k] = 1.f;
                #pragma unroll
                for (int i = 0; i < 4; ++i) {
                    int c = m + 8 * i;
                    rv[k][i] = crow[cj * 32 + ((c + cj) & 31)];
                }
            }
        }
        #pragma unroll
        for (int k = 0; k < 4; ++k) {
            int ci = civ[k];
            float part = 0.f;
            #pragma unroll
            for (int i = 0; i < 4; ++i) {
                int c = m + 8 * i;
                part += dot4(rv[k][i], crow[ci * 32 + ((c + ci) & 31)]);
            }
            part += __shfl_xor(part, 1);
            part += __shfl_xor(part, 2);
            part += __shfl_xor(part, 4);
            if (vv[k]) acc += lsig(sg[k] * part);
        }
    }
    acc += __shfl_xor(acc, 32);
    acc += __shfl_xor(acc, 16);
    acc += __shfl_xor(acc, 8);
    acc += __shfl_xor(acc, 4);
    acc += __shfl_xor(acc, 2);
    acc += __shfl_xor(acc, 1);
    if ((t & 63) == 0) atomicAdd(out, acc * (-1.f / (8.f * (float)BATCH)));
}

extern "C" void kernel_launch(void* const* d_in, const int* in_sizes, int n_in,
                              void* d_out, int out_size, void* d_ws, size_t ws_size,
                              hipStream_t stream) {
    const float* emb  = (const float*)d_in[0];
    const int*   path = (const int*)d_in[1];
    const int*   neg  = (const int*)d_in[2];
    float*       out  = (float*)d_out;

    kzero<<<1, 64, 0, stream>>>(out);

    if (ws_size >= WS_NEEDED) {
        char* ws  = (char*)d_ws;
        u32*  C8  = (u32*)ws;
        int*  cnt = (int*)(ws + CNT_OFF);
        u32*  rec = (u32*)(ws + REC_OFF);

        hipMemsetAsync(cnt, 0, NBUCKET * sizeof(int), stream);
        k_c8 <<<(C_ROWS * 32) / 256, 256, 0, stream>>>(emb, path, C8);
        k_bin<<<NNEG_TOT / 256,      256, 0, stream>>>(neg, cnt, rec);
        k_pos<<<BATCH,               256, 0, stream>>>(emb, path, out);
        k_serve<<<NBUCKET,           256, 0, stream>>>(emb, C8, cnt, rec, out);
    } else {
        mp2v_fallback<<<BATCH * 2, 256, 0, stream>>>(emb, path, neg, out);
    }
}

// Round 11
// 131.214 us; speedup vs baseline: 2.8245x; 2.8245x over previous
//
#include <hip/hip_runtime.h>
#include <math.h>

typedef unsigned int u32;

#define N_TOTAL 500000
#define P_NODES 21
#define KNEG    5
#define DDIM    128
#define BATCH   1024
#define N_PAIRS 185
#define N_NEG   (N_PAIRS * KNEG)            // 925

#define TBL_BYTES ((size_t)N_TOTAL * 128)          // 64 MB fp8 table
#define CONV_BLOCKS ((N_TOTAL * DDIM / 16) / 256)  // 15625

struct Pairs { unsigned char pi[N_PAIRS]; unsigned char pj[N_PAIRS]; };

constexpr Pairs make_pairs() {
    Pairs p{};
    int n = 0;
    for (int i = 0; i < P_NODES; ++i) {
        int jlo = (i - KNEG > 0) ? i - KNEG : 0;
        int jhi = (i + KNEG < P_NODES) ? i + KNEG : P_NODES;
        for (int j = jlo; j < jhi; ++j) { p.pi[n] = (unsigned char)i; p.pj[n] = (unsigned char)j; ++n; }
    }
    return p;
}

__constant__ Pairs PAIRS = make_pairs();

__device__ __forceinline__ float lsig(float x) {
    return -__logf(1.f + __expf(-x));   // dots are tiny; no overflow risk
}

__device__ __forceinline__ float dot4(float4 a, float4 b) {
    return fmaf(a.x, b.x, fmaf(a.y, b.y, fmaf(a.z, b.z, a.w * b.w)));
}

__device__ __forceinline__ int divk(int q) {        // q/5 exact for q < 2^18
    return (int)(((u32)q * 52429u) >> 18);
}

// ---- custom e4m3 (bias 7) codec, pure bit ops (validated R8: absmax 0.0) ----
__device__ __forceinline__ u32 enc1(float x) {
    u32 u = __float_as_uint(x * 0x1p-120f);          // target bits at [26:20]
    u32 s = (u >> 24) & 0x80u;
    u &= 0x7fffffffu;
    u += 0x7FFFFu + ((u >> 20) & 1u);                // RNE at bit 20
    return s | ((u >> 20) & 0x7fu);
}
__device__ __forceinline__ float dec1(u32 b) {
    u32 bits = ((b << 20) & 0x07f00000u) | ((b << 24) & 0x80000000u);
    return __uint_as_float(bits) * 0x1p+120f;
}
__device__ __forceinline__ float dot_pk(u32 d, float4 c) {
    float r;
    r  = dec1( d         & 0xffu) * c.x;
    r += dec1((d >>  8u) & 0xffu) * c.y;
    r += dec1((d >> 16u) & 0xffu) * c.z;
    r += dec1( d >> 24u         ) * c.w;
    return r;
}

__global__ void kzero(float* __restrict__ out) {
    if (threadIdx.x == 0) out[0] = 0.f;
}

// ---- k_conv: stream f32 table -> fp8 table (1 line per row), plain cached loads ----
__global__ __launch_bounds__(256) void k_conv(const float4* __restrict__ src,
                                              uint4* __restrict__ dst) {
    int t = blockIdx.x * 256 + threadIdx.x;          // 4,000,000 threads, 16 elems each
    float4 a = src[4 * (size_t)t + 0];
    float4 b = src[4 * (size_t)t + 1];
    float4 c = src[4 * (size_t)t + 2];
    float4 d = src[4 * (size_t)t + 3];
    u32 w0 = enc1(a.x) | (enc1(a.y) << 8) | (enc1(a.z) << 16) | (enc1(a.w) << 24);
    u32 w1 = enc1(b.x) | (enc1(b.y) << 8) | (enc1(b.z) << 16) | (enc1(b.w) << 24);
    u32 w2 = enc1(c.x) | (enc1(c.y) << 8) | (enc1(c.z) << 16) | (enc1(c.w) << 24);
    u32 w3 = enc1(d.x) | (enc1(d.y) << 8) | (enc1(d.z) << 16) | (enc1(d.w) << 24);
    dst[t] = make_uint4(w0, w1, w2, w3);
}

// ---- k_main: ONE block per b; LANE-PER-TASK negs (each load instr = 64 distinct
// 128B lines; a lane's 8 uint4 loads hit ITS one line -> MSHR-coalesced, row fully
// consumed). 2-deep software pipeline -> up to 128 lines outstanding per wave. ----
__global__ __launch_bounds__(256) void k_main(
    const float* __restrict__ emb,
    const int*   __restrict__ path,
    const int*   __restrict__ neg,
    const uint4* __restrict__ tbl4,
    float*       __restrict__ out)
{
    __shared__ float4 crow[P_NODES * 32];     // 10.5 KB f32 c-rows, slot rotated by row
    __shared__ int    nidx[N_NEG];
    __shared__ int    pidx[P_NODES];
    __shared__ unsigned char spi[N_PAIRS];
    __shared__ unsigned char spj[N_PAIRS];

    const int b = blockIdx.x;
    const int t = threadIdx.x;

    if (t < P_NODES) pidx[t] = path[b * P_NODES + t];
    if (t < N_PAIRS) { spi[t] = PAIRS.pi[t]; spj[t] = PAIRS.pj[t]; }
    for (int q = t; q < N_NEG; q += 256) {
        int p = divk(q);
        int k = q - p * KNEG;
        nidx[q] = neg[(size_t)p * (BATCH * KNEG) + b * KNEG + k];
    }
    __syncthreads();   // pidx ready
    for (int e = t; e < P_NODES * 32; e += 256) {
        int r = e >> 5, c = e & 31;
        float4 val = ((const float4*)(emb + (size_t)pidx[r] * DDIM))[c];
        crow[r * 32 + ((c + r) & 31)] = val;
    }
    __syncthreads();   // crow + nidx ready; no more barriers

    float acc = 0.f;

    // ---- neg: lane-per-task, 4 iterations (256*4 = 1024 >= 925), 2-stage pipeline ----
    uint4 r[8], n[8];
    int q = t;                                 // t < 256 <= 925: always valid first task
    {
        const uint4* R = tbl4 + (size_t)nidx[q] * 8;
        #pragma unroll
        for (int j = 0; j < 8; ++j) r[j] = R[j];
    }
    #pragma unroll
    for (int it = 0; it < 4; ++it) {
        const int qn = q + 256;
        if (it < 3) {
            const uint4* Rn = tbl4 + (size_t)nidx[qn < N_NEG ? qn : 0] * 8;
            #pragma unroll
            for (int j = 0; j < 8; ++j) n[j] = Rn[j];
        }
        if (q < N_NEG) {
            const int ci = spi[divk(q)];
            const float4* cr = &crow[ci * 32];
            float part = 0.f;
            #pragma unroll
            for (int j = 0; j < 8; ++j) {
                part += dot_pk(r[j].x, cr[(4 * j + 0 + ci) & 31]);
                part += dot_pk(r[j].y, cr[(4 * j + 1 + ci) & 31]);
                part += dot_pk(r[j].z, cr[(4 * j + 2 + ci) & 31]);
                part += dot_pk(r[j].w, cr[(4 * j + 3 + ci) & 31]);
            }
            acc += lsig(-part);
        }
        #pragma unroll
        for (int j = 0; j < 8; ++j) r[j] = n[j];
        q = qn;
    }

    // ---- pos: lane-per-task from LDS (exact f32) ----
    if (t < N_PAIRS) {
        const int ci = spi[t], cj = spj[t];
        const float4* cri = &crow[ci * 32];
        const float4* crj = &crow[cj * 32];
        float part = 0.f;
        #pragma unroll
        for (int s = 0; s < 32; ++s)
            part += dot4(cri[(s + ci) & 31], crj[(s + cj) & 31]);
        acc += lsig(part);
    }

    // ---- wave reduce, one atomic per wave ----
    acc += __shfl_xor(acc, 32);
    acc += __shfl_xor(acc, 16);
    acc += __shfl_xor(acc, 8);
    acc += __shfl_xor(acc, 4);
    acc += __shfl_xor(acc, 2);
    acc += __shfl_xor(acc, 1);
    if ((t & 63) == 0)
        atomicAdd(out, acc * (-1.f / (float)BATCH));
}

// ================= fallback (R6 kernel, verbatim) if ws is too small =================
#define NTASK_F (N_PAIRS + N_NEG)
#define HALF_T  (NTASK_F / 2)

__global__ __launch_bounds__(256) void mp2v_fallback(
    const float* __restrict__ emb, const int* __restrict__ path,
    const int* __restrict__ neg, float* __restrict__ out)
{
    __shared__ float4 crow[P_NODES * 32];
    __shared__ int    nidxf[N_NEG];
    __shared__ int    pidx[P_NODES];
    __shared__ unsigned char spi[N_PAIRS];
    __shared__ unsigned char spj[N_PAIRS];

    const int blk = blockIdx.x;
    const int b   = blk >> 1;
    const int q0  = (blk & 1) * HALF_T;
    const int q1  = q0 + HALF_T;
    const int t   = threadIdx.x;

    if (t < P_NODES) pidx[t] = path[b * P_NODES + t];
    if (t < N_PAIRS) { spi[t] = PAIRS.pi[t]; spj[t] = PAIRS.pj[t]; }
    for (int q = t; q < N_NEG; q += 256) {
        int p = divk(q);
        int k = q - p * KNEG;
        nidxf[q] = neg[(size_t)p * (BATCH * KNEG) + b * KNEG + k];
    }
    __syncthreads();
    for (int e = t; e < P_NODES * 32; e += 256) {
        int r = e >> 5, c = e & 31;
        float4 val = ((const float4*)(emb + (size_t)pidx[r] * DDIM))[c];
        crow[r * 32 + ((c + r) & 31)] = val;
    }
    __syncthreads();

    const int g = t >> 3, m = t & 7;
    const float4* emb4 = (const float4*)emb;
    float acc = 0.f;

    for (int base = q0; base < q1; base += 128) {
        float4 rv[4][4];
        int civ[4]; float sg[4]; bool vv[4];
        #pragma unroll
        for (int k = 0; k < 4; ++k) {
            int qq = base + g * 4 + k;
            bool v = qq < q1; vv[k] = v;
            int qc = v ? qq : q0;
            if (qc < N_NEG) {
                int p = divk(qc);
                civ[k] = spi[p]; sg[k] = -1.f;
                const float4* R = emb4 + (size_t)nidxf[qc] * 32;
                #pragma unroll
                for (int i = 0; i < 4; ++i) rv[k][i] = R[m + 8 * i];
            } else {
                int pp = qc - N_NEG;
                int cj = spj[pp];
                civ[k] = spi[pp]; sg[k] = 1.f;
                #pragma unroll
                for (int i = 0; i < 4; ++i) {
                    int c = m + 8 * i;
                    rv[k][i] = crow[cj * 32 + ((c + cj) & 31)];
                }
            }
        }
        #pragma unroll
        for (int k = 0; k < 4; ++k) {
            int ci = civ[k];
            float part = 0.f;
            #pragma unroll
            for (int i = 0; i < 4; ++i) {
                int c = m + 8 * i;
                part += dot4(rv[k][i], crow[ci * 32 + ((c + ci) & 31)]);
            }
            part += __shfl_xor(part, 1);
            part += __shfl_xor(part, 2);
            part += __shfl_xor(part, 4);
            if (vv[k]) acc += lsig(sg[k] * part);
        }
    }
    acc += __shfl_xor(acc, 32);
    acc += __shfl_xor(acc, 16);
    acc += __shfl_xor(acc, 8);
    acc += __shfl_xor(acc, 4);
    acc += __shfl_xor(acc, 2);
    acc += __shfl_xor(acc, 1);
    if ((t & 63) == 0) atomicAdd(out, acc * (-1.f / (8.f * (float)BATCH)));
}

extern "C" void kernel_launch(void* const* d_in, const int* in_sizes, int n_in,
                              void* d_out, int out_size, void* d_ws, size_t ws_size,
                              hipStream_t stream) {
    const float* emb  = (const float*)d_in[0];
    const int*   path = (const int*)d_in[1];
    const int*   neg  = (const int*)d_in[2];
    float*       out  = (float*)d_out;

    kzero<<<1, 64, 0, stream>>>(out);

    if (ws_size >= TBL_BYTES) {
        k_conv<<<CONV_BLOCKS, 256, 0, stream>>>((const float4*)emb, (uint4*)d_ws);
        k_main<<<BATCH, 256, 0, stream>>>(emb, path, neg, (const uint4*)d_ws, out);
    } else {
        mp2v_fallback<<<BATCH * 2, 256, 0, stream>>>(emb, path, neg, out);
    }
}

// Round 12
// 128.295 us; speedup vs baseline: 2.8888x; 1.0227x over previous
//
#include <hip/hip_runtime.h>
#include <math.h>

typedef unsigned int u32;
typedef float vf2 __attribute__((ext_vector_type(2)));

#define N_TOTAL 500000
#define P_NODES 21
#define KNEG    5
#define DDIM    128
#define BATCH   1024
#define N_PAIRS 185
#define N_NEG   (N_PAIRS * KNEG)            // 925

#define TBL_BYTES ((size_t)N_TOTAL * 128)          // 64 MB fp8 table
#define CONV_BLOCKS ((N_TOTAL * DDIM / 16) / 256)  // 15625

struct Pairs { unsigned char pi[N_PAIRS]; unsigned char pj[N_PAIRS]; };

constexpr Pairs make_pairs() {
    Pairs p{};
    int n = 0;
    for (int i = 0; i < P_NODES; ++i) {
        int jlo = (i - KNEG > 0) ? i - KNEG : 0;
        int jhi = (i + KNEG < P_NODES) ? i + KNEG : P_NODES;
        for (int j = jlo; j < jhi; ++j) { p.pi[n] = (unsigned char)i; p.pj[n] = (unsigned char)j; ++n; }
    }
    return p;
}

__constant__ Pairs PAIRS = make_pairs();

__device__ __forceinline__ float lsig(float x) {
    return -__logf(1.f + __expf(-x));   // dots are tiny; no overflow risk
}

__device__ __forceinline__ float dot4(float4 a, float4 b) {
    return fmaf(a.x, b.x, fmaf(a.y, b.y, fmaf(a.z, b.z, a.w * b.w)));
}

__device__ __forceinline__ int divk(int q) {        // q/5 exact for q < 2^18
    return (int)(((u32)q * 52429u) >> 18);
}

// ---- HW OCP-e4m3 codec (gfx950). Encode+decode both HW -> self-consistent. ----
__device__ __forceinline__ u32 enc_pk4(float4 v) {
    int d = 0;
    d = __builtin_amdgcn_cvt_pk_fp8_f32(v.x, v.y, d, false);   // bytes 0,1
    d = __builtin_amdgcn_cvt_pk_fp8_f32(v.z, v.w, d, true);    // bytes 2,3
    return (u32)d;
}
__device__ __forceinline__ float dot_pk(u32 d, float4 c) {
    vf2 lo = __builtin_amdgcn_cvt_pk_f32_fp8((int)d, false);   // bytes 0,1
    vf2 hi = __builtin_amdgcn_cvt_pk_f32_fp8((int)d, true);    // bytes 2,3
    return fmaf(lo.x, c.x, fmaf(lo.y, c.y, fmaf(hi.x, c.z, hi.y * c.w)));
}

__global__ void kzero(float* __restrict__ out) {
    if (threadIdx.x == 0) out[0] = 0.f;
}

// ---- k_conv: stream f32 table -> fp8 table (1 line per row), HW encode ----
__global__ __launch_bounds__(256) void k_conv(const float4* __restrict__ src,
                                              uint4* __restrict__ dst) {
    int t = blockIdx.x * 256 + threadIdx.x;          // 4,000,000 threads, 16 elems each
    float4 a = src[4 * (size_t)t + 0];
    float4 b = src[4 * (size_t)t + 1];
    float4 c = src[4 * (size_t)t + 2];
    float4 d = src[4 * (size_t)t + 3];
    dst[t] = make_uint4(enc_pk4(a), enc_pk4(b), enc_pk4(c), enc_pk4(d));
}

// ---- k_main: ONE block per b; LANE-PER-TASK negs (each load instr = 64 distinct
// 128B lines; a lane's 8 uint4 loads hit ITS one line -> coalesced into 1 request,
// row fully consumed). 2-deep pipeline; HW fp8 decode (~7 VALU/dword vs 30). ----
__global__ __launch_bounds__(256) void k_main(
    const float* __restrict__ emb,
    const int*   __restrict__ path,
    const int*   __restrict__ neg,
    const uint4* __restrict__ tbl4,
    float*       __restrict__ out)
{
    __shared__ float4 crow[P_NODES * 32];     // 10.5 KB f32 c-rows, slot rotated by row
    __shared__ int    nidx[N_NEG];
    __shared__ int    pidx[P_NODES];
    __shared__ unsigned char spi[N_PAIRS];
    __shared__ unsigned char spj[N_PAIRS];

    const int b = blockIdx.x;
    const int t = threadIdx.x;

    if (t < P_NODES) pidx[t] = path[b * P_NODES + t];
    if (t < N_PAIRS) { spi[t] = PAIRS.pi[t]; spj[t] = PAIRS.pj[t]; }
    for (int q = t; q < N_NEG; q += 256) {
        int p = divk(q);
        int k = q - p * KNEG;
        nidx[q] = neg[(size_t)p * (BATCH * KNEG) + b * KNEG + k];
    }
    __syncthreads();   // pidx ready
    for (int e = t; e < P_NODES * 32; e += 256) {
        int r = e >> 5, c = e & 31;
        float4 val = ((const float4*)(emb + (size_t)pidx[r] * DDIM))[c];
        crow[r * 32 + ((c + r) & 31)] = val;
    }
    __syncthreads();   // crow + nidx ready; no more barriers

    float acc = 0.f;

    // ---- neg: lane-per-task, 4 iterations (256*4 = 1024 >= 925), 2-stage pipeline ----
    uint4 r[8], n[8];
    int q = t;                                 // t < 256 <= 925: always valid first task
    {
        const uint4* R = tbl4 + (size_t)nidx[q] * 8;
        #pragma unroll
        for (int j = 0; j < 8; ++j) r[j] = R[j];
    }
    #pragma unroll
    for (int it = 0; it < 4; ++it) {
        const int qn = q + 256;
        if (it < 3) {
            const uint4* Rn = tbl4 + (size_t)nidx[qn < N_NEG ? qn : 0] * 8;
            #pragma unroll
            for (int j = 0; j < 8; ++j) n[j] = Rn[j];
        }
        if (q < N_NEG) {
            const int ci = spi[divk(q)];
            const float4* cr = &crow[ci * 32];
            float part = 0.f;
            #pragma unroll
            for (int j = 0; j < 8; ++j) {
                part += dot_pk(r[j].x, cr[(4 * j + 0 + ci) & 31]);
                part += dot_pk(r[j].y, cr[(4 * j + 1 + ci) & 31]);
                part += dot_pk(r[j].z, cr[(4 * j + 2 + ci) & 31]);
                part += dot_pk(r[j].w, cr[(4 * j + 3 + ci) & 31]);
            }
            acc += lsig(-part);
        }
        #pragma unroll
        for (int j = 0; j < 8; ++j) r[j] = n[j];
        q = qn;
    }

    // ---- pos: lane-per-task from LDS (exact f32) ----
    if (t < N_PAIRS) {
        const int ci = spi[t], cj = spj[t];
        const float4* cri = &crow[ci * 32];
        const float4* crj = &crow[cj * 32];
        float part = 0.f;
        #pragma unroll
        for (int s = 0; s < 32; ++s)
            part += dot4(cri[(s + ci) & 31], crj[(s + cj) & 31]);
        acc += lsig(part);
    }

    // ---- wave reduce, one atomic per wave ----
    acc += __shfl_xor(acc, 32);
    acc += __shfl_xor(acc, 16);
    acc += __shfl_xor(acc, 8);
    acc += __shfl_xor(acc, 4);
    acc += __shfl_xor(acc, 2);
    acc += __shfl_xor(acc, 1);
    if ((t & 63) == 0)
        atomicAdd(out, acc * (-1.f / (float)BATCH));
}

// ================= fallback (R6 kernel, verbatim) if ws is too small =================
#define NTASK_F (N_PAIRS + N_NEG)
#define HALF_T  (NTASK_F / 2)

__global__ __launch_bounds__(256) void mp2v_fallback(
    const float* __restrict__ emb, const int* __restrict__ path,
    const int* __restrict__ neg, float* __restrict__ out)
{
    __shared__ float4 crow[P_NODES * 32];
    __shared__ int    nidxf[N_NEG];
    __shared__ int    pidx[P_NODES];
    __shared__ unsigned char spi[N_PAIRS];
    __shared__ unsigned char spj[N_PAIRS];

    const int blk = blockIdx.x;
    const int b   = blk >> 1;
    const int q0  = (blk & 1) * HALF_T;
    const int q1  = q0 + HALF_T;
    const int t   = threadIdx.x;

    if (t < P_NODES) pidx[t] = path[b * P_NODES + t];
    if (t < N_PAIRS) { spi[t] = PAIRS.pi[t]; spj[t] = PAIRS.pj[t]; }
    for (int q = t; q < N_NEG; q += 256) {
        int p = divk(q);
        int k = q - p * KNEG;
        nidxf[q] = neg[(size_t)p * (BATCH * KNEG) + b * KNEG + k];
    }
    __syncthreads();
    for (int e = t; e < P_NODES * 32; e += 256) {
        int r = e >> 5, c = e & 31;
        float4 val = ((const float4*)(emb + (size_t)pidx[r] * DDIM))[c];
        crow[r * 32 + ((c + r) & 31)] = val;
    }
    __syncthreads();

    const int g = t >> 3, m = t & 7;
    const float4* emb4 = (const float4*)emb;
    float acc = 0.f;

    for (int base = q0; base < q1; base += 128) {
        float4 rv[4][4];
        int civ[4]; float sg[4]; bool vv[4];
        #pragma unroll
        for (int k = 0; k < 4; ++k) {
            int qq = base + g * 4 + k;
            bool v = qq < q1; vv[k] = v;
            int qc = v ? qq : q0;
            if (qc < N_NEG) {
                int p = divk(qc);
                civ[k] = spi[p]; sg[k] = -1.f;
                const float4* R = emb4 + (size_t)nidxf[qc] * 32;
                #pragma unroll
                for (int i = 0; i < 4; ++i) rv[k][i] = R[m + 8 * i];
            } else {
                int pp = qc - N_NEG;
                int cj = spj[pp];
                civ[k] = spi[pp]; sg[k] = 1.f;
                #pragma unroll
                for (int i = 0; i < 4; ++i) {
                    int c = m + 8 * i;
                    rv[k][i] = crow[cj * 32 + ((c + cj) & 31)];
                }
            }
        }
        #pragma unroll
        for (int k = 0; k < 4; ++k) {
            int ci = civ[k];
            float part = 0.f;
            #pragma unroll
            for (int i = 0; i < 4; ++i) {
                int c = m + 8 * i;
                part += dot4(rv[k][i], crow[ci * 32 + ((c + ci) & 31)]);
            }
            part += __shfl_xor(part, 1);
            part += __shfl_xor(part, 2);
            part += __shfl_xor(part, 4);
            if (vv[k]) acc += lsig(sg[k] * part);
        }
    }
    acc += __shfl_xor(acc, 32);
    acc += __shfl_xor(acc, 16);
    acc += __shfl_xor(acc, 8);
    acc += __shfl_xor(acc, 4);
    acc += __shfl_xor(acc, 2);
    acc += __shfl_xor(acc, 1);
    if ((t & 63) == 0) atomicAdd(out, acc * (-1.f / (8.f * (float)BATCH)));
}

extern "C" void kernel_launch(void* const* d_in, const int* in_sizes, int n_in,
                              void* d_out, int out_size, void* d_ws, size_t ws_size,
                              hipStream_t stream) {
    const float* emb  = (const float*)d_in[0];
    const int*   path = (const int*)d_in[1];
    const int*   neg  = (const int*)d_in[2];
    float*       out  = (float*)d_out;

    kzero<<<1, 64, 0, stream>>>(out);

    if (ws_size >= TBL_BYTES) {
        k_conv<<<CONV_BLOCKS, 256, 0, stream>>>((const float4*)emb, (uint4*)d_ws);
        k_main<<<BATCH, 256, 0, stream>>>(emb, path, neg, (const uint4*)d_ws, out);
    } else {
        mp2v_fallback<<<BATCH * 2, 256, 0, stream>>>(emb, path, neg, out);
    }
}